// Round 3
// baseline (449.478 us; speedup 1.0000x reference)
//
#include <hip/hip_runtime.h>
#include <hip/hip_cooperative_groups.h>
#include <math.h>

namespace cg = cooperative_groups;

// DecoderLayer: B=4,N=1,S=256,D=128,H=128,DFF=512, fp32 end-to-end.
// Round-2: ONE cooperative dispatch, 8 stages separated by grid.sync().
//  Stage A: weight prep  C?? = Ww@W1?, combined bias vectors (b1/bw folded)
//  Stage B: 6 projections from x/enc (xw,qa,kb | kv2w,kb2,ka2)
//  Stage C: self pairwise (single term; symmetric term via transpose in D)
//  Stage D: softmax(+sym transpose)+AV+out-proj+residual+LN -> out1  (fused, AV stays in LDS)
//  Stage F: q-side cross projections out1 -> qa2,qb2
//  Stage G: cross pairwise, both symmetric terms
//  Stage H: softmax+AV+out-proj+residual+LN -> out2
//  Stage J: ffn1+relu+ffn2+residual+LN -> out (fused, hidden stays in LDS)
// b2 dropped (softmax shift invariance). RES_RATIO=1 -> plain residual add.

#define LN_EPS 1e-6f
#define NEGV  (-1e9f)

constexpr int B = 4, S = 256, D = 128, H = 128, DFF = 512;
constexpr int R = B * S;          // 1024 rows (N=1)
constexpr int GRID = 256;         // 1 block/CU -> cooperative co-residency guaranteed
constexpr int LDW = H + 4;        // padded pairwise LDS stride (16B-aligned rows)
constexpr int SMEM_FLOATS = 64 * LDW + H;  // pairwise is the max user: 8576 floats = 34.3 KB

struct P {
    const float *x, *enc, *com_mask, *dec_mask;
    const float *W1q, *W1k, *b1, *W2;
    const float *Ww1, *bw1, *Wd1, *bd1;
    const float *Ww2, *bw2, *Wd2, *bd2;
    const float *Wf1, *bf1, *Wf2, *bf2;
    const float *ln1g, *ln1b, *ln2g, *ln2b, *ln3g, *ln3b;
    float *out;
    // workspace
    float *C1q, *C1k, *C2q, *C2k, *bb;
    float *xw, *qa, *kb, *kv2w, *kb2, *ka2, *qa2, *qb2;
    float *sbuf, *out1, *out2;
};

// ---- 8-row projection: out[r0..r0+7][0..127] = A[rows]@W + bias; whole block ----
__device__ __forceinline__ void proj8(const float* __restrict__ A,
                                      const float* __restrict__ W,
                                      const float* __restrict__ bias,
                                      float* __restrict__ out,
                                      int r0, float* Ash, int tid)
{
    __syncthreads();  // protect Ash from previous user
    ((float4*)Ash)[tid] = ((const float4*)(A + (size_t)r0 * 128))[tid]; // 8*128 = 256 float4
    __syncthreads();
    const int lr = tid >> 5, c4 = tid & 31;
    const float4* W4 = (const float4*)W;
    float4 acc = bias ? ((const float4*)bias)[c4] : make_float4(0.f, 0.f, 0.f, 0.f);
    #pragma unroll 8
    for (int k = 0; k < 128; ++k) {
        const float a = Ash[lr * 128 + k];
        const float4 w = W4[k * 32 + c4];
        acc.x = fmaf(a, w.x, acc.x); acc.y = fmaf(a, w.y, acc.y);
        acc.z = fmaf(a, w.z, acc.z); acc.w = fmaf(a, w.w, acc.w);
    }
    ((float4*)out)[(size_t)(r0 + lr) * 32 + c4] = acc;
}

// ---- pairwise accumulate helper (float4 over h) ----
#define PW_STEP(AP0, AP1, BP0, BP1)                                            \
    {                                                                          \
        const float4 w  = *(const float4*)(W2s + h);                           \
        const float4 a0 = *(const float4*)((AP0) + h);                         \
        const float4 a1 = *(const float4*)((AP1) + h);                         \
        const float4 b0 = *(const float4*)((BP0) + h);                         \
        const float4 b1 = *(const float4*)((BP1) + h);                         \
        acc00 = fmaf(fmaxf(a0.x+b0.x,0.f),w.x,acc00); acc00 = fmaf(fmaxf(a0.y+b0.y,0.f),w.y,acc00); \
        acc00 = fmaf(fmaxf(a0.z+b0.z,0.f),w.z,acc00); acc00 = fmaf(fmaxf(a0.w+b0.w,0.f),w.w,acc00); \
        acc01 = fmaf(fmaxf(a0.x+b1.x,0.f),w.x,acc01); acc01 = fmaf(fmaxf(a0.y+b1.y,0.f),w.y,acc01); \
        acc01 = fmaf(fmaxf(a0.z+b1.z,0.f),w.z,acc01); acc01 = fmaf(fmaxf(a0.w+b1.w,0.f),w.w,acc01); \
        acc10 = fmaf(fmaxf(a1.x+b0.x,0.f),w.x,acc10); acc10 = fmaf(fmaxf(a1.y+b0.y,0.f),w.y,acc10); \
        acc10 = fmaf(fmaxf(a1.z+b0.z,0.f),w.z,acc10); acc10 = fmaf(fmaxf(a1.w+b0.w,0.f),w.w,acc10); \
        acc11 = fmaf(fmaxf(a1.x+b1.x,0.f),w.x,acc11); acc11 = fmaf(fmaxf(a1.y+b1.y,0.f),w.y,acc11); \
        acc11 = fmaf(fmaxf(a1.z+b1.z,0.f),w.z,acc11); acc11 = fmaf(fmaxf(a1.w+b1.w,0.f),w.w,acc11); \
    }

// ---- fused softmax (+sym transpose) + AV + out-proj + residual + LN ----
__device__ __forceinline__ void attn_tail(const P& p, float* smem, int tid, int blk,
    bool sym, const float* __restrict__ mask, const float* __restrict__ V,
    const float* __restrict__ Wd, const float* __restrict__ bd,
    const float* __restrict__ res, const float* __restrict__ lg,
    const float* __restrict__ lb, float* __restrict__ outp)
{
    if (blk >= 128) return;
    float* s8  = smem;          // 8*256
    float* aoS = smem + 2048;   // 8*128
    const int r0 = blk * 8, b = r0 >> 8, bS = b * S;

    for (int i = tid; i < 8 * S; i += 256) {
        const int r = i >> 8, k = i & 255;
        const int row = r0 + r, q = row & 255;
        float l = p.sbuf[(size_t)row * S + k];
        if (sym) l += p.sbuf[(size_t)(bS + k) * S + q];
        l += mask[(size_t)row * S + k] * NEGV;
        s8[i] = l;
    }
    __syncthreads();
    {
        const int g = tid >> 5, c = tid & 31;
        float* rowp = s8 + g * S;
        float m = -INFINITY;
        for (int k = c; k < S; k += 32) m = fmaxf(m, rowp[k]);
        for (int o = 16; o; o >>= 1) m = fmaxf(m, __shfl_xor(m, o, 32));
        float s = 0.f;
        for (int k = c; k < S; k += 32) { const float e = __expf(rowp[k] - m); rowp[k] = e; s += e; }
        for (int o = 16; o; o >>= 1) s += __shfl_xor(s, o, 32);
        const float rinv = 1.f / s;
        for (int k = c; k < S; k += 32) rowp[k] *= rinv;
    }
    __syncthreads();
    const int lr = tid >> 5, c4 = tid & 31;
    {
        const float4* V4 = (const float4*)(V + (size_t)bS * D);
        float4 acc = make_float4(0.f, 0.f, 0.f, 0.f);
        #pragma unroll 8
        for (int k = 0; k < S; ++k) {
            const float a = s8[lr * 256 + k];
            const float4 v = V4[k * 32 + c4];
            acc.x = fmaf(a, v.x, acc.x); acc.y = fmaf(a, v.y, acc.y);
            acc.z = fmaf(a, v.z, acc.z); acc.w = fmaf(a, v.w, acc.w);
        }
        ((float4*)(aoS + lr * 128))[c4] = acc;
    }
    __syncthreads();
    const float4* W4 = (const float4*)Wd;
    float4 o = ((const float4*)bd)[c4];
    #pragma unroll 8
    for (int k = 0; k < 128; ++k) {
        const float a = aoS[lr * 128 + k];
        const float4 w = W4[k * 32 + c4];
        o.x = fmaf(a, w.x, o.x); o.y = fmaf(a, w.y, o.y);
        o.z = fmaf(a, w.z, o.z); o.w = fmaf(a, w.w, o.w);
    }
    const float4 r4 = ((const float4*)(res + (size_t)(r0 + lr) * 128))[c4];
    const float x0 = o.x + r4.x, x1 = o.y + r4.y, x2 = o.z + r4.z, x3 = o.w + r4.w;
    float s  = x0 + x1 + x2 + x3;
    float s2 = x0 * x0 + x1 * x1 + x2 * x2 + x3 * x3;
    for (int of = 16; of; of >>= 1) { s += __shfl_xor(s, of, 32); s2 += __shfl_xor(s2, of, 32); }
    const float m = s * (1.f / 128), var = s2 * (1.f / 128) - m * m;
    const float rs = rsqrtf(var + LN_EPS);
    const float4 gv = ((const float4*)lg)[c4], bv = ((const float4*)lb)[c4];
    float4 o4;
    o4.x = (x0 - m) * rs * gv.x + bv.x; o4.y = (x1 - m) * rs * gv.y + bv.y;
    o4.z = (x2 - m) * rs * gv.z + bv.z; o4.w = (x3 - m) * rs * gv.w + bv.w;
    ((float4*)outp)[(size_t)(r0 + lr) * 32 + c4] = o4;
}

__global__ __launch_bounds__(256) void fused_decoder(P p)
{
    cg::grid_group grid = cg::this_grid();
    __shared__ __align__(16) float smem[SMEM_FLOATS];
    const int tid = threadIdx.x;
    const int blk = blockIdx.x;

    // ================= Stage A: weight/bias prep =================
    if (blk < 64) {
        const float* Lm[4] = { p.Ww1, p.Ww1, p.Ww2, p.Ww2 };
        const float* Rm[4] = { p.W1q, p.W1k, p.W1q, p.W1k };
        float*       Om[4] = { p.C1q, p.C1k, p.C2q, p.C2k };
        const int m = blk >> 4, r0 = (blk & 15) * 8;
        proj8(Lm[m], Rm[m], nullptr, Om[m], r0, smem, tid);
    } else if (blk < 70) {
        if (tid < 128) {
            const int j = blk - 64;
            const float* bwj[6] = { p.bw1, p.bw1, p.bw2, p.bw2, p.bw2, p.bw2 };
            const float* Wrj[6] = { p.W1q, p.W1k, p.W1q, p.W1k, p.W1k, p.W1q };
            const int addb1[6]  = { 1, 0, 1, 1, 0, 0 }; // qa, kb, qa2, qb2, kb2, ka2
            const float* bw = bwj[j];
            const float* Wr = Wrj[j];
            float s = addb1[j] ? p.b1[tid] : 0.f;
            #pragma unroll 8
            for (int k = 0; k < 128; ++k) s = fmaf(bw[k], Wr[k * 128 + tid], s);
            p.bb[j * 128 + tid] = s;
        }
    }
    grid.sync();

    // ================= Stage B: 6 projections from x/enc =================
    for (int u = blk; u < 768; u += GRID) {
        const int half = u >= 384;            // 0: self(x), 1: cross(enc)
        const int lu = u - half * 384;
        const int g = lu >> 7;                // 0..2
        const int r0 = (lu & 127) * 8;
        const float* A = half ? p.enc : p.x;
        const float* W; const float* bias; float* o;
        if (!half) {
            if (g == 0)      { W = p.Ww1; bias = p.bw1;       o = p.xw; }
            else if (g == 1) { W = p.C1q; bias = p.bb;        o = p.qa; }
            else             { W = p.C1k; bias = p.bb + 128;  o = p.kb; }
        } else {
            if (g == 0)      { W = p.Ww2; bias = p.bw2;       o = p.kv2w; }
            else if (g == 1) { W = p.C2k; bias = p.bb + 512;  o = p.kb2; }
            else             { W = p.C2q; bias = p.bb + 640;  o = p.ka2; }
        }
        proj8(A, W, bias, o, r0, smem, tid);
    }
    grid.sync();

    // ================= Stage C: self pairwise (single term) =================
    {
        float* As  = smem;
        float* Bs  = smem + 32 * LDW;
        float* W2s = smem + 64 * LDW;
        const int b = blk >> 6, q0 = ((blk >> 3) & 7) * 32, k0 = (blk & 7) * 32;
        const int bS = b * S;
        for (int i = tid; i < 32 * (H / 4); i += 256) {
            const int r = i >> 5, c4 = i & 31;
            ((float4*)(As + r * LDW))[c4] = ((const float4*)(p.qa + (size_t)(bS + q0 + r) * H))[c4];
            ((float4*)(Bs + r * LDW))[c4] = ((const float4*)(p.kb + (size_t)(bS + k0 + r) * H))[c4];
        }
        if (tid < H / 4) ((float4*)W2s)[tid] = ((const float4*)p.W2)[tid];
        __syncthreads();
        const int tx = tid & 15, ty = tid >> 4;
        const float* A0 = As + (2 * ty) * LDW; const float* A1 = A0 + LDW;
        const float* B0 = Bs + (2 * tx) * LDW; const float* B1 = B0 + LDW;
        float acc00 = 0.f, acc01 = 0.f, acc10 = 0.f, acc11 = 0.f;
        #pragma unroll 4
        for (int h = 0; h < H; h += 4) PW_STEP(A0, A1, B0, B1);
        const size_t base = (size_t)(bS + q0 + 2 * ty) * S + (k0 + 2 * tx);
        *(float2*)(p.sbuf + base)     = make_float2(acc00, acc01);
        *(float2*)(p.sbuf + base + S) = make_float2(acc10, acc11);
    }
    grid.sync();

    // ================= Stage D: self softmax+AV+proj+LN -> out1 =================
    attn_tail(p, smem, tid, blk, true, p.com_mask, p.xw, p.Wd1, p.bd1,
              p.x, p.ln1g, p.ln1b, p.out1);
    grid.sync();

    // ================= Stage F: cross q-side projections =================
    {
        const int g = blk >> 7, r0 = (blk & 127) * 8;
        const float* W    = g ? p.C2k        : p.C2q;
        const float* bias = g ? (p.bb + 384) : (p.bb + 256);
        float* o          = g ? p.qb2        : p.qa2;
        proj8(p.out1, W, bias, o, r0, smem, tid);
    }
    grid.sync();

    // ================= Stage G: cross pairwise, both terms =================
    {
        float* As  = smem;
        float* Bs  = smem + 32 * LDW;
        float* W2s = smem + 64 * LDW;
        const int b = blk >> 6, q0 = ((blk >> 3) & 7) * 32, k0 = (blk & 7) * 32;
        const int bS = b * S;
        const int tx = tid & 15, ty = tid >> 4;
        const float* A0 = As + (2 * ty) * LDW; const float* A1 = A0 + LDW;
        const float* B0 = Bs + (2 * tx) * LDW; const float* B1 = B0 + LDW;
        float acc00 = 0.f, acc01 = 0.f, acc10 = 0.f, acc11 = 0.f;

        __syncthreads();  // smem handoff from stage F
        for (int i = tid; i < 32 * (H / 4); i += 256) {
            const int r = i >> 5, c4 = i & 31;
            ((float4*)(As + r * LDW))[c4] = ((const float4*)(p.qa2 + (size_t)(bS + q0 + r) * H))[c4];
            ((float4*)(Bs + r * LDW))[c4] = ((const float4*)(p.kb2 + (size_t)(bS + k0 + r) * H))[c4];
        }
        if (tid < H / 4) ((float4*)W2s)[tid] = ((const float4*)p.W2)[tid];
        __syncthreads();
        #pragma unroll 4
        for (int h = 0; h < H; h += 4) PW_STEP(A0, A1, B0, B1);
        __syncthreads();
        for (int i = tid; i < 32 * (H / 4); i += 256) {
            const int r = i >> 5, c4 = i & 31;
            ((float4*)(As + r * LDW))[c4] = ((const float4*)(p.qb2 + (size_t)(bS + q0 + r) * H))[c4];
            ((float4*)(Bs + r * LDW))[c4] = ((const float4*)(p.ka2 + (size_t)(bS + k0 + r) * H))[c4];
        }
        __syncthreads();
        #pragma unroll 4
        for (int h = 0; h < H; h += 4) PW_STEP(A0, A1, B0, B1);
        const size_t base = (size_t)(bS + q0 + 2 * ty) * S + (k0 + 2 * tx);
        *(float2*)(p.sbuf + base)     = make_float2(acc00, acc01);
        *(float2*)(p.sbuf + base + S) = make_float2(acc10, acc11);
    }
    grid.sync();

    // ================= Stage H: cross softmax+AV+proj+LN -> out2 =================
    attn_tail(p, smem, tid, blk, false, p.dec_mask, p.kv2w, p.Wd2, p.bd2,
              p.out1, p.ln2g, p.ln2b, p.out2);
    grid.sync();

    // ================= Stage J: ffn1+relu+ffn2+residual+LN -> out =================
    if (blk < 128) {
        float* o2S = smem;          // 8*128
        float* fhS = smem + 1024;   // 8*512
        const int r0 = blk * 8;
        __syncthreads();
        ((float4*)o2S)[tid] = ((const float4*)(p.out2 + (size_t)r0 * 128))[tid];
        __syncthreads();
        const int lr = tid >> 5, c4 = tid & 31;
        const float4* Wf1_4 = (const float4*)p.Wf1;
        const float4* bf1_4 = (const float4*)p.bf1;
        float4 a0 = bf1_4[c4], a1 = bf1_4[c4 + 32], a2 = bf1_4[c4 + 64], a3 = bf1_4[c4 + 96];
        #pragma unroll 4
        for (int k = 0; k < 128; ++k) {
            const float a = o2S[lr * 128 + k];
            const float4 w0 = Wf1_4[k * 128 + c4];
            const float4 w1 = Wf1_4[k * 128 + c4 + 32];
            const float4 w2 = Wf1_4[k * 128 + c4 + 64];
            const float4 w3 = Wf1_4[k * 128 + c4 + 96];
            a0.x = fmaf(a, w0.x, a0.x); a0.y = fmaf(a, w0.y, a0.y);
            a0.z = fmaf(a, w0.z, a0.z); a0.w = fmaf(a, w0.w, a0.w);
            a1.x = fmaf(a, w1.x, a1.x); a1.y = fmaf(a, w1.y, a1.y);
            a1.z = fmaf(a, w1.z, a1.z); a1.w = fmaf(a, w1.w, a1.w);
            a2.x = fmaf(a, w2.x, a2.x); a2.y = fmaf(a, w2.y, a2.y);
            a2.z = fmaf(a, w2.z, a2.z); a2.w = fmaf(a, w2.w, a2.w);
            a3.x = fmaf(a, w3.x, a3.x); a3.y = fmaf(a, w3.y, a3.y);
            a3.z = fmaf(a, w3.z, a3.z); a3.w = fmaf(a, w3.w, a3.w);
        }
        a0.x = fmaxf(a0.x, 0.f); a0.y = fmaxf(a0.y, 0.f); a0.z = fmaxf(a0.z, 0.f); a0.w = fmaxf(a0.w, 0.f);
        a1.x = fmaxf(a1.x, 0.f); a1.y = fmaxf(a1.y, 0.f); a1.z = fmaxf(a1.z, 0.f); a1.w = fmaxf(a1.w, 0.f);
        a2.x = fmaxf(a2.x, 0.f); a2.y = fmaxf(a2.y, 0.f); a2.z = fmaxf(a2.z, 0.f); a2.w = fmaxf(a2.w, 0.f);
        a3.x = fmaxf(a3.x, 0.f); a3.y = fmaxf(a3.y, 0.f); a3.z = fmaxf(a3.z, 0.f); a3.w = fmaxf(a3.w, 0.f);
        float4* fh4 = (float4*)(fhS + lr * 512);
        fh4[c4] = a0; fh4[c4 + 32] = a1; fh4[c4 + 64] = a2; fh4[c4 + 96] = a3;
        __syncthreads();
        const float4* Wf2_4 = (const float4*)p.Wf2;
        float4 o = ((const float4*)p.bf2)[c4];
        #pragma unroll 8
        for (int k = 0; k < 512; ++k) {
            const float a = fhS[lr * 512 + k];
            const float4 w = Wf2_4[k * 32 + c4];
            o.x = fmaf(a, w.x, o.x); o.y = fmaf(a, w.y, o.y);
            o.z = fmaf(a, w.z, o.z); o.w = fmaf(a, w.w, o.w);
        }
        const float4 r4 = ((const float4*)(o2S + lr * 128))[c4];  // residual from LDS
        const float x0 = o.x + r4.x, x1 = o.y + r4.y, x2 = o.z + r4.z, x3 = o.w + r4.w;
        float s  = x0 + x1 + x2 + x3;
        float s2 = x0 * x0 + x1 * x1 + x2 * x2 + x3 * x3;
        for (int of = 16; of; of >>= 1) { s += __shfl_xor(s, of, 32); s2 += __shfl_xor(s2, of, 32); }
        const float m = s * (1.f / 128), var = s2 * (1.f / 128) - m * m;
        const float rs = rsqrtf(var + LN_EPS);
        const float4 gv = ((const float4*)p.ln3g)[c4], bv = ((const float4*)p.ln3b)[c4];
        float4 o4;
        o4.x = (x0 - m) * rs * gv.x + bv.x; o4.y = (x1 - m) * rs * gv.y + bv.y;
        o4.z = (x2 - m) * rs * gv.z + bv.z; o4.w = (x3 - m) * rs * gv.w + bv.w;
        ((float4*)p.out)[(size_t)(r0 + lr) * 32 + c4] = o4;
    }
}

extern "C" void kernel_launch(void* const* d_in, const int* in_sizes, int n_in,
                              void* d_out, int out_size, void* d_ws, size_t ws_size,
                              hipStream_t stream) {
    (void)in_sizes; (void)n_in; (void)out_size; (void)ws_size;
    P p;
    p.x        = (const float*)d_in[0];
    p.enc      = (const float*)d_in[1];
    p.com_mask = (const float*)d_in[2];
    p.dec_mask = (const float*)d_in[3];
    p.W1q = (const float*)d_in[4];
    p.W1k = (const float*)d_in[5];
    p.b1  = (const float*)d_in[6];
    p.W2  = (const float*)d_in[7];
    // d_in[8] = b2: constant per softmax row -> dropped (shift invariance)
    p.Ww1 = (const float*)d_in[9];
    p.bw1 = (const float*)d_in[10];
    p.Wd1 = (const float*)d_in[11];
    p.bd1 = (const float*)d_in[12];
    p.Ww2 = (const float*)d_in[13];
    p.bw2 = (const float*)d_in[14];
    p.Wd2 = (const float*)d_in[15];
    p.bd2 = (const float*)d_in[16];
    p.Wf1 = (const float*)d_in[17];
    p.bf1 = (const float*)d_in[18];
    p.Wf2 = (const float*)d_in[19];
    p.bf2 = (const float*)d_in[20];
    p.ln1g = (const float*)d_in[21];
    p.ln1b = (const float*)d_in[22];
    p.ln2g = (const float*)d_in[23];
    p.ln2b = (const float*)d_in[24];
    p.ln3g = (const float*)d_in[25];
    p.ln3b = (const float*)d_in[26];
    p.out  = (float*)d_out;

    float* ws = (float*)d_ws;
    const size_t RD  = (size_t)R * D;      // 131072
    const size_t SSz = (size_t)B * S * S;  // 262144
    const size_t WW  = 128 * 128;          // 16384
    p.C1q  = ws;
    p.C1k  = p.C1q  + WW;
    p.C2q  = p.C1k  + WW;
    p.C2k  = p.C2q  + WW;
    p.bb   = p.C2k  + WW;     // [6][128]
    p.xw   = p.bb   + 1024;
    p.qa   = p.xw   + RD;
    p.kb   = p.qa   + RD;
    p.kv2w = p.kb   + RD;
    p.kb2  = p.kv2w + RD;
    p.ka2  = p.kb2  + RD;
    p.qa2  = p.ka2  + RD;
    p.qb2  = p.qa2  + RD;
    p.sbuf = p.qb2  + RD;     // SSz
    p.out1 = p.sbuf + SSz;
    p.out2 = p.out1 + RD;

    void* args[] = { &p };
    hipLaunchCooperativeKernel((void*)fused_decoder, dim3(GRID), dim3(256),
                               args, 0, stream);
}

// Round 4
// 224.855 us; speedup vs baseline: 1.9990x; 1.9990x over previous
//
#include <hip/hip_runtime.h>
#include <math.h>

// DecoderLayer: B=4,N=1,S=256,D=128,H=128,DFF=512, fp32 end-to-end.
// Round-3 post-mortem: cooperative grid.sync costs ~40us each on MI355X
// (XCD-L2 flush) -> single-kernel path abandoned. Round-4: 7 dispatches.
//  1. prep: C?? = Ww@W1? (4 mats) + 6 combined bias vectors (b1/bw folded)
//  2. proj6: x -> xw,qa,kb ; enc -> kv2w,kb2,ka2   (one kernel, grid.y=6)
//  3. pairwise_self (sym term = transpose, read in stage 4)
//  4. attn_tail1: softmax(+sym)+AV+outproj+res+LN -> out1, PLUS qa2,qb2 proj
//  5. pairwise_cross2 (both symmetric terms, two-phase LDS)
//  6. attn_tail2: softmax+AV+outproj+res+LN -> out2
//  7. ffn: ffn1+relu (LDS) + ffn2+res+LN -> out   (4 rows/block, grid=256)
// b2 dropped (softmax shift invariance). RES_RATIO=1 -> plain residual add.

#define LN_EPS 1e-6f
#define NEGV  (-1e9f)

constexpr int B = 4, S = 256, D = 128, H = 128, DFF = 512;
constexpr int R = B * S;   // 1024 rows (N=1)
constexpr int LDW = H + 4; // padded pairwise LDS stride (16B-aligned rows)

struct P {
    const float *x, *enc, *com_mask, *dec_mask;
    const float *W1q, *W1k, *b1, *W2;
    const float *Ww1, *bw1, *Wd1, *bd1;
    const float *Ww2, *bw2, *Wd2, *bd2;
    const float *Wf1, *bf1, *Wf2, *bf2;
    const float *ln1g, *ln1b, *ln2g, *ln2b, *ln3g, *ln3b;
    float *out;
    float *C1q, *C1k, *C2q, *C2k, *bb;
    float *xw, *qa, *kb, *kv2w, *kb2, *ka2, *qa2, *qb2;
    float *sbuf, *sbuf2, *out1, *out2;
};

// ================= 1: weight/bias prep =================
// blocks 0..63: C[m] = L[m]@R[m] (8 rows each); blocks 64..69: bias combos.
__global__ __launch_bounds__(256) void prep_kernel(P p)
{
    const int blk = blockIdx.x, tid = threadIdx.x;
    if (blk < 64) {
        const float* Lm[4] = { p.Ww1, p.Ww1, p.Ww2, p.Ww2 };
        const float* Rm[4] = { p.W1q, p.W1k, p.W1q, p.W1k };
        float*       Om[4] = { p.C1q, p.C1k, p.C2q, p.C2k };
        const int m = blk >> 4, r0 = (blk & 15) * 8;
        __shared__ float Ash[8 * 128];
        ((float4*)Ash)[tid] = ((const float4*)(Lm[m] + (size_t)r0 * 128))[tid];
        __syncthreads();
        const int lr = tid >> 5, c4 = tid & 31;
        const float4* W4 = (const float4*)Rm[m];
        float4 acc = make_float4(0.f, 0.f, 0.f, 0.f);
        #pragma unroll 8
        for (int k = 0; k < 128; ++k) {
            const float a = Ash[lr * 128 + k];
            const float4 w = W4[k * 32 + c4];
            acc.x = fmaf(a, w.x, acc.x); acc.y = fmaf(a, w.y, acc.y);
            acc.z = fmaf(a, w.z, acc.z); acc.w = fmaf(a, w.w, acc.w);
        }
        ((float4*)Om[m])[(size_t)(r0 + lr) * 32 + c4] = acc;
    } else if (tid < 128) {
        const int j = blk - 64;
        const float* bwj[6] = { p.bw1, p.bw1, p.bw2, p.bw2, p.bw2, p.bw2 };
        const float* Wrj[6] = { p.W1q, p.W1k, p.W1q, p.W1k, p.W1k, p.W1q };
        const int addb1[6]  = { 1, 0, 1, 1, 0, 0 }; // qa, kb, qa2, qb2, kb2, ka2
        const float* bw = bwj[j];
        const float* Wr = Wrj[j];
        float s = addb1[j] ? p.b1[tid] : 0.f;
        #pragma unroll 8
        for (int k = 0; k < 128; ++k) s = fmaf(bw[k], Wr[k * 128 + tid], s);
        p.bb[j * 128 + tid] = s;
    }
}

// ================= 2: six projections, grid (R/8, 6) =================
__global__ __launch_bounds__(256) void proj6_kernel(P p)
{
    const int g = blockIdx.y, tid = threadIdx.x;
    const float* A; const float* W; const float* bias; float* o;
    switch (g) {
        case 0: A = p.x;   W = p.Ww1; bias = p.bw1;       o = p.xw;   break;
        case 1: A = p.x;   W = p.C1q; bias = p.bb;        o = p.qa;   break;
        case 2: A = p.x;   W = p.C1k; bias = p.bb + 128;  o = p.kb;   break;
        case 3: A = p.enc; W = p.Ww2; bias = p.bw2;       o = p.kv2w; break;
        case 4: A = p.enc; W = p.C2k; bias = p.bb + 512;  o = p.kb2;  break;
        default:A = p.enc; W = p.C2q; bias = p.bb + 640;  o = p.ka2;  break;
    }
    __shared__ float Ash[8 * 128];
    const int r0 = blockIdx.x * 8;
    ((float4*)Ash)[tid] = ((const float4*)(A + (size_t)r0 * 128))[tid];
    __syncthreads();
    const int lr = tid >> 5, c4 = tid & 31;
    const float4* W4 = (const float4*)W;
    float4 acc = ((const float4*)bias)[c4];
    #pragma unroll 8
    for (int k = 0; k < 128; ++k) {
        const float a = Ash[lr * 128 + k];
        const float4 w = W4[k * 32 + c4];
        acc.x = fmaf(a, w.x, acc.x); acc.y = fmaf(a, w.y, acc.y);
        acc.z = fmaf(a, w.z, acc.z); acc.w = fmaf(a, w.w, acc.w);
    }
    ((float4*)o)[(size_t)(r0 + lr) * 32 + c4] = acc;
}

// ---- pairwise accumulate helper (float4 over h) ----
#define PW_STEP(AP0, AP1, BP0, BP1)                                            \
    {                                                                          \
        const float4 w  = *(const float4*)(W2s + h);                           \
        const float4 a0 = *(const float4*)((AP0) + h);                         \
        const float4 a1 = *(const float4*)((AP1) + h);                         \
        const float4 b0 = *(const float4*)((BP0) + h);                         \
        const float4 b1 = *(const float4*)((BP1) + h);                         \
        acc00 = fmaf(fmaxf(a0.x+b0.x,0.f),w.x,acc00); acc00 = fmaf(fmaxf(a0.y+b0.y,0.f),w.y,acc00); \
        acc00 = fmaf(fmaxf(a0.z+b0.z,0.f),w.z,acc00); acc00 = fmaf(fmaxf(a0.w+b0.w,0.f),w.w,acc00); \
        acc01 = fmaf(fmaxf(a0.x+b1.x,0.f),w.x,acc01); acc01 = fmaf(fmaxf(a0.y+b1.y,0.f),w.y,acc01); \
        acc01 = fmaf(fmaxf(a0.z+b1.z,0.f),w.z,acc01); acc01 = fmaf(fmaxf(a0.w+b1.w,0.f),w.w,acc01); \
        acc10 = fmaf(fmaxf(a1.x+b0.x,0.f),w.x,acc10); acc10 = fmaf(fmaxf(a1.y+b0.y,0.f),w.y,acc10); \
        acc10 = fmaf(fmaxf(a1.z+b0.z,0.f),w.z,acc10); acc10 = fmaf(fmaxf(a1.w+b0.w,0.f),w.w,acc10); \
        acc11 = fmaf(fmaxf(a1.x+b1.x,0.f),w.x,acc11); acc11 = fmaf(fmaxf(a1.y+b1.y,0.f),w.y,acc11); \
        acc11 = fmaf(fmaxf(a1.z+b1.z,0.f),w.z,acc11); acc11 = fmaf(fmaxf(a1.w+b1.w,0.f),w.w,acc11); \
    }

// ================= 3: self pairwise (single term) =================
__global__ __launch_bounds__(256) void pairwise_self_kernel(P p)
{
    __shared__ __align__(16) float As[32 * LDW];
    __shared__ __align__(16) float Bs[32 * LDW];
    __shared__ __align__(16) float W2s[H];
    const int b = blockIdx.z, q0 = blockIdx.y * 32, k0 = blockIdx.x * 32;
    const int tid = threadIdx.x, bS = b * S;
    for (int i = tid; i < 32 * (H / 4); i += 256) {
        const int r = i >> 5, c4 = i & 31;
        ((float4*)(As + r * LDW))[c4] = ((const float4*)(p.qa + (size_t)(bS + q0 + r) * H))[c4];
        ((float4*)(Bs + r * LDW))[c4] = ((const float4*)(p.kb + (size_t)(bS + k0 + r) * H))[c4];
    }
    if (tid < H / 4) ((float4*)W2s)[tid] = ((const float4*)p.W2)[tid];
    __syncthreads();
    const int tx = tid & 15, ty = tid >> 4;
    const float* A0 = As + (2 * ty) * LDW; const float* A1 = A0 + LDW;
    const float* B0 = Bs + (2 * tx) * LDW; const float* B1 = B0 + LDW;
    float acc00 = 0.f, acc01 = 0.f, acc10 = 0.f, acc11 = 0.f;
    #pragma unroll 4
    for (int h = 0; h < H; h += 4) PW_STEP(A0, A1, B0, B1);
    const size_t base = (size_t)(bS + q0 + 2 * ty) * S + (k0 + 2 * tx);
    *(float2*)(p.sbuf + base)     = make_float2(acc00, acc01);
    *(float2*)(p.sbuf + base + S) = make_float2(acc10, acc11);
}

// ================= 5: cross pairwise, both symmetric terms =================
__global__ __launch_bounds__(256) void pairwise_cross2_kernel(P p)
{
    __shared__ __align__(16) float As[32 * LDW];
    __shared__ __align__(16) float Bs[32 * LDW];
    __shared__ __align__(16) float W2s[H];
    const int b = blockIdx.z, q0 = blockIdx.y * 32, k0 = blockIdx.x * 32;
    const int tid = threadIdx.x, bS = b * S;
    const int tx = tid & 15, ty = tid >> 4;
    const float* A0 = As + (2 * ty) * LDW; const float* A1 = A0 + LDW;
    const float* B0 = Bs + (2 * tx) * LDW; const float* B1 = B0 + LDW;
    float acc00 = 0.f, acc01 = 0.f, acc10 = 0.f, acc11 = 0.f;

    for (int i = tid; i < 32 * (H / 4); i += 256) {
        const int r = i >> 5, c4 = i & 31;
        ((float4*)(As + r * LDW))[c4] = ((const float4*)(p.qa2 + (size_t)(bS + q0 + r) * H))[c4];
        ((float4*)(Bs + r * LDW))[c4] = ((const float4*)(p.kb2 + (size_t)(bS + k0 + r) * H))[c4];
    }
    if (tid < H / 4) ((float4*)W2s)[tid] = ((const float4*)p.W2)[tid];
    __syncthreads();
    #pragma unroll 4
    for (int h = 0; h < H; h += 4) PW_STEP(A0, A1, B0, B1);
    __syncthreads();
    for (int i = tid; i < 32 * (H / 4); i += 256) {
        const int r = i >> 5, c4 = i & 31;
        ((float4*)(As + r * LDW))[c4] = ((const float4*)(p.qb2 + (size_t)(bS + q0 + r) * H))[c4];
        ((float4*)(Bs + r * LDW))[c4] = ((const float4*)(p.ka2 + (size_t)(bS + k0 + r) * H))[c4];
    }
    __syncthreads();
    #pragma unroll 4
    for (int h = 0; h < H; h += 4) PW_STEP(A0, A1, B0, B1);
    const size_t base = (size_t)(bS + q0 + 2 * ty) * S + (k0 + 2 * tx);
    *(float2*)(p.sbuf2 + base)     = make_float2(acc00, acc01);
    *(float2*)(p.sbuf2 + base + S) = make_float2(acc10, acc11);
}

// ================= 4/6: softmax(+sym)+AV+outproj+res+LN (+q-side proj) =================
template<bool SYM, bool QPROJ>
__global__ __launch_bounds__(256) void attn_tail_kernel(P p)
{
    __shared__ float s8[8 * 256];
    __shared__ float aoS[8 * 128];
    __shared__ float o1S[8 * 128];
    const float* Sin  = SYM ? p.sbuf : p.sbuf2;
    const float* mask = SYM ? p.com_mask : p.dec_mask;
    const float* V    = SYM ? p.xw : p.kv2w;
    const float* Wd   = SYM ? p.Wd1 : p.Wd2;
    const float* bd   = SYM ? p.bd1 : p.bd2;
    const float* res  = SYM ? p.x : p.out1;
    const float* lg   = SYM ? p.ln1g : p.ln2g;
    const float* lb   = SYM ? p.ln1b : p.ln2b;
    float* outp       = SYM ? p.out1 : p.out2;

    const int tid = threadIdx.x;
    const int r0 = blockIdx.x * 8, b = r0 >> 8, bS = b * S;

    for (int i = tid; i < 8 * 256; i += 256) {
        const int r = i >> 8, k = i & 255;
        const int row = r0 + r, q = row & 255;
        float l = Sin[(size_t)row * S + k];
        if (SYM) l += Sin[(size_t)(bS + k) * S + q];
        l += mask[(size_t)row * S + k] * NEGV;
        s8[i] = l;
    }
    __syncthreads();
    {
        const int g = tid >> 5, c = tid & 31;
        float* rowp = s8 + g * 256;
        float m = -INFINITY;
        for (int k = c; k < 256; k += 32) m = fmaxf(m, rowp[k]);
        for (int o = 16; o; o >>= 1) m = fmaxf(m, __shfl_xor(m, o, 32));
        float s = 0.f;
        for (int k = c; k < 256; k += 32) { const float e = __expf(rowp[k] - m); rowp[k] = e; s += e; }
        for (int o = 16; o; o >>= 1) s += __shfl_xor(s, o, 32);
        const float rinv = 1.f / s;
        for (int k = c; k < 256; k += 32) rowp[k] *= rinv;
    }
    __syncthreads();
    const int lr = tid >> 5, c4 = tid & 31;
    {
        const float4* V4 = (const float4*)(V + (size_t)bS * D);
        float4 acc = make_float4(0.f, 0.f, 0.f, 0.f);
        #pragma unroll 8
        for (int k = 0; k < 256; ++k) {
            const float a = s8[lr * 256 + k];
            const float4 v = V4[k * 32 + c4];
            acc.x = fmaf(a, v.x, acc.x); acc.y = fmaf(a, v.y, acc.y);
            acc.z = fmaf(a, v.z, acc.z); acc.w = fmaf(a, v.w, acc.w);
        }
        ((float4*)(aoS + lr * 128))[c4] = acc;
    }
    __syncthreads();
    {
        const float4* W4 = (const float4*)Wd;
        float4 o = ((const float4*)bd)[c4];
        #pragma unroll 8
        for (int k = 0; k < 128; ++k) {
            const float a = aoS[lr * 128 + k];
            const float4 w = W4[k * 32 + c4];
            o.x = fmaf(a, w.x, o.x); o.y = fmaf(a, w.y, o.y);
            o.z = fmaf(a, w.z, o.z); o.w = fmaf(a, w.w, o.w);
        }
        const float4 r4 = ((const float4*)(res + (size_t)(r0 + lr) * 128))[c4];
        const float x0 = o.x + r4.x, x1 = o.y + r4.y, x2 = o.z + r4.z, x3 = o.w + r4.w;
        float s  = x0 + x1 + x2 + x3;
        float s2 = x0 * x0 + x1 * x1 + x2 * x2 + x3 * x3;
        for (int of = 16; of; of >>= 1) { s += __shfl_xor(s, of, 32); s2 += __shfl_xor(s2, of, 32); }
        const float m = s * (1.f / 128), var = s2 * (1.f / 128) - m * m;
        const float rs = rsqrtf(var + LN_EPS);
        const float4 gv = ((const float4*)lg)[c4], bv = ((const float4*)lb)[c4];
        float4 o4;
        o4.x = (x0 - m) * rs * gv.x + bv.x; o4.y = (x1 - m) * rs * gv.y + bv.y;
        o4.z = (x2 - m) * rs * gv.z + bv.z; o4.w = (x3 - m) * rs * gv.w + bv.w;
        ((float4*)outp)[(size_t)(r0 + lr) * 32 + c4] = o4;
        if (QPROJ) { ((float4*)(o1S + lr * 128))[c4] = o4; }
    }
    if (QPROJ) {
        // qa2 = out1@C2q + bb[2]; qb2 = out1@C2k + bb[3]  (out1 rows in LDS)
        __syncthreads();
        const float* Wq[2]  = { p.C2q, p.C2k };
        const float* bq[2]  = { p.bb + 256, p.bb + 384 };
        float* oq[2]        = { p.qa2, p.qb2 };
        #pragma unroll
        for (int g = 0; g < 2; ++g) {
            const float4* W4 = (const float4*)Wq[g];
            float4 o = ((const float4*)bq[g])[c4];
            #pragma unroll 8
            for (int k = 0; k < 128; ++k) {
                const float a = o1S[lr * 128 + k];
                const float4 w = W4[k * 32 + c4];
                o.x = fmaf(a, w.x, o.x); o.y = fmaf(a, w.y, o.y);
                o.z = fmaf(a, w.z, o.z); o.w = fmaf(a, w.w, o.w);
            }
            ((float4*)oq[g])[(size_t)(r0 + lr) * 32 + c4] = o;
        }
    }
}

// ================= 7: ffn1+relu+ffn2+res+LN, 4 rows/block =================
__global__ __launch_bounds__(256) void ffn_kernel(P p)
{
    __shared__ float o2S[4 * 128];
    __shared__ float fhS[4 * 512];
    __shared__ float part[4 * 2 * 128];
    const int r0 = blockIdx.x * 4, tid = threadIdx.x;
    const int row = tid >> 6, t = tid & 63;

    if (tid < 128) ((float4*)o2S)[tid] = ((const float4*)(p.out2 + (size_t)r0 * 128))[tid];
    __syncthreads();

    // ffn1: thread -> row `row`, float4 cols t and t+64 (512 cols = 128 float4)
    const float4* Wf1_4 = (const float4*)p.Wf1;
    const float4* bf1_4 = (const float4*)p.bf1;
    float4 a0 = bf1_4[t], a1 = bf1_4[t + 64];
    #pragma unroll 8
    for (int k = 0; k < 128; ++k) {
        const float a = o2S[row * 128 + k];
        const float4 w0 = Wf1_4[k * 128 + t];
        const float4 w1 = Wf1_4[k * 128 + t + 64];
        a0.x = fmaf(a, w0.x, a0.x); a0.y = fmaf(a, w0.y, a0.y);
        a0.z = fmaf(a, w0.z, a0.z); a0.w = fmaf(a, w0.w, a0.w);
        a1.x = fmaf(a, w1.x, a1.x); a1.y = fmaf(a, w1.y, a1.y);
        a1.z = fmaf(a, w1.z, a1.z); a1.w = fmaf(a, w1.w, a1.w);
    }
    a0.x = fmaxf(a0.x, 0.f); a0.y = fmaxf(a0.y, 0.f); a0.z = fmaxf(a0.z, 0.f); a0.w = fmaxf(a0.w, 0.f);
    a1.x = fmaxf(a1.x, 0.f); a1.y = fmaxf(a1.y, 0.f); a1.z = fmaxf(a1.z, 0.f); a1.w = fmaxf(a1.w, 0.f);
    {
        float4* fh4 = (float4*)(fhS + row * 512);
        fh4[t] = a0; fh4[t + 64] = a1;
    }
    __syncthreads();

    // ffn2: k-split by 2; thread -> row, kh = t>>5, c4 = t&31; 256-MAC partial
    const int kh = t >> 5, c4 = t & 31;
    const float4* Wf2_4 = (const float4*)p.Wf2;
    float4 acc = make_float4(0.f, 0.f, 0.f, 0.f);
    const float* fhp = fhS + row * 512 + kh * 256;
    #pragma unroll 8
    for (int k = 0; k < 256; ++k) {
        const float a = fhp[k];
        const float4 w = Wf2_4[(kh * 256 + k) * 32 + c4];
        acc.x = fmaf(a, w.x, acc.x); acc.y = fmaf(a, w.y, acc.y);
        acc.z = fmaf(a, w.z, acc.z); acc.w = fmaf(a, w.w, acc.w);
    }
    ((float4*)part)[(row * 2 + kh) * 32 + c4] = acc;
    __syncthreads();

    if (kh == 0) {  // lanes 0..31 of each wave; shuffle width 32 stays in-half
        const float4 p0 = ((const float4*)part)[(row * 2 + 0) * 32 + c4];
        const float4 p1 = ((const float4*)part)[(row * 2 + 1) * 32 + c4];
        const float4 bf = ((const float4*)p.bf2)[c4];
        const float4 r4 = ((const float4*)o2S)[row * 32 + c4];
        const float x0 = p0.x + p1.x + bf.x + r4.x;
        const float x1 = p0.y + p1.y + bf.y + r4.y;
        const float x2 = p0.z + p1.z + bf.z + r4.z;
        const float x3 = p0.w + p1.w + bf.w + r4.w;
        float s  = x0 + x1 + x2 + x3;
        float s2 = x0 * x0 + x1 * x1 + x2 * x2 + x3 * x3;
        for (int of = 16; of; of >>= 1) { s += __shfl_xor(s, of, 32); s2 += __shfl_xor(s2, of, 32); }
        const float m = s * (1.f / 128), var = s2 * (1.f / 128) - m * m;
        const float rs = rsqrtf(var + LN_EPS);
        const float4 gv = ((const float4*)p.ln3g)[c4], bv = ((const float4*)p.ln3b)[c4];
        float4 o4;
        o4.x = (x0 - m) * rs * gv.x + bv.x; o4.y = (x1 - m) * rs * gv.y + bv.y;
        o4.z = (x2 - m) * rs * gv.z + bv.z; o4.w = (x3 - m) * rs * gv.w + bv.w;
        ((float4*)p.out)[(size_t)(r0 + row) * 32 + c4] = o4;
    }
}

extern "C" void kernel_launch(void* const* d_in, const int* in_sizes, int n_in,
                              void* d_out, int out_size, void* d_ws, size_t ws_size,
                              hipStream_t stream) {
    (void)in_sizes; (void)n_in; (void)out_size; (void)ws_size;
    P p;
    p.x        = (const float*)d_in[0];
    p.enc      = (const float*)d_in[1];
    p.com_mask = (const float*)d_in[2];
    p.dec_mask = (const float*)d_in[3];
    p.W1q = (const float*)d_in[4];
    p.W1k = (const float*)d_in[5];
    p.b1  = (const float*)d_in[6];
    p.W2  = (const float*)d_in[7];
    // d_in[8] = b2: per-row constant -> dropped (softmax shift invariance)
    p.Ww1 = (const float*)d_in[9];
    p.bw1 = (const float*)d_in[10];
    p.Wd1 = (const float*)d_in[11];
    p.bd1 = (const float*)d_in[12];
    p.Ww2 = (const float*)d_in[13];
    p.bw2 = (const float*)d_in[14];
    p.Wd2 = (const float*)d_in[15];
    p.bd2 = (const float*)d_in[16];
    p.Wf1 = (const float*)d_in[17];
    p.bf1 = (const float*)d_in[18];
    p.Wf2 = (const float*)d_in[19];
    p.bf2 = (const float*)d_in[20];
    p.ln1g = (const float*)d_in[21];
    p.ln1b = (const float*)d_in[22];
    p.ln2g = (const float*)d_in[23];
    p.ln2b = (const float*)d_in[24];
    p.ln3g = (const float*)d_in[25];
    p.ln3b = (const float*)d_in[26];
    p.out  = (float*)d_out;

    float* ws = (float*)d_ws;
    const size_t RD  = (size_t)R * D;      // 131072
    const size_t SSz = (size_t)B * S * S;  // 262144
    const size_t WW  = 128 * 128;          // 16384
    p.C1q   = ws;
    p.C1k   = p.C1q   + WW;
    p.C2q   = p.C1k   + WW;
    p.C2k   = p.C2q   + WW;
    p.bb    = p.C2k   + WW;    // [6][128]
    p.xw    = p.bb    + 1024;
    p.qa    = p.xw    + RD;
    p.kb    = p.qa    + RD;
    p.kv2w  = p.kb    + RD;
    p.kb2   = p.kv2w  + RD;
    p.ka2   = p.kb2   + RD;
    p.qa2   = p.ka2   + RD;
    p.qb2   = p.qa2   + RD;
    p.sbuf  = p.qb2   + RD;    // SSz
    p.sbuf2 = p.sbuf  + SSz;   // SSz
    p.out1  = p.sbuf2 + SSz;
    p.out2  = p.out1  + RD;

    prep_kernel<<<70, 256, 0, stream>>>(p);
    proj6_kernel<<<dim3(R / 8, 6), 256, 0, stream>>>(p);
    pairwise_self_kernel<<<dim3(8, 8, 4), 256, 0, stream>>>(p);
    attn_tail_kernel<true, true><<<R / 8, 256, 0, stream>>>(p);
    pairwise_cross2_kernel<<<dim3(8, 8, 4), 256, 0, stream>>>(p);
    attn_tail_kernel<false, false><<<R / 8, 256, 0, stream>>>(p);
    ffn_kernel<<<R / 4, 256, 0, stream>>>(p);
}

// Round 5
// 198.997 us; speedup vs baseline: 2.2587x; 1.1299x over previous
//
#include <hip/hip_runtime.h>
#include <math.h>

// DecoderLayer: B=4,N=1,S=256,D=128,H=128,DFF=512, fp32 end-to-end.
// Round-5: 6 dispatches.
//  1. proj3: x -> xw -> {qa,kb} ; enc -> kv2w -> {kb2,ka2}  (chained via LDS,
//     no precombined weights -> prep kernel eliminated)
//  2. pairwise_self (sym term = transpose, read in stage 3)
//  3. attn_tail1: softmax(+sym)+AV+outproj+res+LN -> out1, then epilogue
//     out1 -> q2w -> {qa2,qb2} chained through LDS
//  4. pairwise_cross2 (both symmetric terms, two-phase LDS)
//  5. attn_tail2: softmax+AV+outproj+res+LN -> out2
//  6. ffn: register-tiled — each Wf1/Wf2 float4 loaded ONCE per block and
//     reused across 4 rows in registers (round-4 ffn re-read weights 4x
//     through L1 and ran 42us at 4 waves/CU).
// b2 dropped (softmax shift invariance). RES_RATIO=1 -> plain residual add.

#define LN_EPS 1e-6f
#define NEGV  (-1e9f)

constexpr int B = 4, S = 256, D = 128, H = 128, DFF = 512;
constexpr int R = B * S;   // 1024 rows (N=1)
constexpr int LDW = H + 4; // padded pairwise LDS stride (16B-aligned rows)

struct P {
    const float *x, *enc, *com_mask, *dec_mask;
    const float *W1q, *W1k, *b1, *W2;
    const float *Ww1, *bw1, *Wd1, *bd1;
    const float *Ww2, *bw2, *Wd2, *bd2;
    const float *Wf1, *bf1, *Wf2, *bf2;
    const float *ln1g, *ln1b, *ln2g, *ln2b, *ln3g, *ln3b;
    float *out;
    float *xw, *qa, *kb, *kv2w, *kb2, *ka2, *qa2, *qb2;
    float *sbuf, *sbuf2, *out1, *out2;
};

// ---- in-LDS 8-row x 128 matmul helper: dst4 = AshS@W (+bias) ----
__device__ __forceinline__ float4 mm8(const float* AshS, const float* W,
                                      const float* bias, int lr, int c4)
{
    const float4* W4 = (const float4*)W;
    float4 acc = bias ? ((const float4*)bias)[c4] : make_float4(0.f, 0.f, 0.f, 0.f);
    #pragma unroll 8
    for (int k = 0; k < 128; ++k) {
        const float a = AshS[lr * 128 + k];
        const float4 w = W4[k * 32 + c4];
        acc.x = fmaf(a, w.x, acc.x); acc.y = fmaf(a, w.y, acc.y);
        acc.z = fmaf(a, w.z, acc.z); acc.w = fmaf(a, w.w, acc.w);
    }
    return acc;
}

// ================= 1: chained projections, grid (R/8, 2) =================
__global__ __launch_bounds__(256) void proj3_kernel(P p)
{
    const int g = blockIdx.y, tid = threadIdx.x;
    const int r0 = blockIdx.x * 8;
    const int lr = tid >> 5, c4 = tid & 31;
    __shared__ float Ash[8 * 128];
    __shared__ float Pw[8 * 128];

    const float* A    = g ? p.enc  : p.x;
    const float* Wp   = g ? p.Ww2  : p.Ww1;
    const float* bp   = g ? p.bw2  : p.bw1;
    float*       o_w  = g ? p.kv2w : p.xw;
    const float* Wsec = g ? p.W1k  : p.W1q;  // kb2 | qa
    const float* bsec = g ? nullptr: p.b1;
    float*       o_s  = g ? p.kb2  : p.qa;
    const float* Wthr = g ? p.W1q  : p.W1k;  // ka2 | kb
    float*       o_t  = g ? p.ka2  : p.kb;

    ((float4*)Ash)[tid] = ((const float4*)(A + (size_t)r0 * 128))[tid];
    __syncthreads();
    {
        const float4 w = mm8(Ash, Wp, bp, lr, c4);
        ((float4*)(Pw + lr * 128))[c4] = w;
        ((float4*)o_w)[(size_t)(r0 + lr) * 32 + c4] = w;
    }
    __syncthreads();
    {
        const float4 q = mm8(Pw, Wsec, bsec, lr, c4);
        ((float4*)o_s)[(size_t)(r0 + lr) * 32 + c4] = q;
        const float4 k = mm8(Pw, Wthr, nullptr, lr, c4);
        ((float4*)o_t)[(size_t)(r0 + lr) * 32 + c4] = k;
    }
}

// ---- pairwise accumulate helper (float4 over h) ----
#define PW_STEP(AP0, AP1, BP0, BP1)                                            \
    {                                                                          \
        const float4 w  = *(const float4*)(W2s + h);                           \
        const float4 a0 = *(const float4*)((AP0) + h);                         \
        const float4 a1 = *(const float4*)((AP1) + h);                         \
        const float4 b0 = *(const float4*)((BP0) + h);                         \
        const float4 b1 = *(const float4*)((BP1) + h);                         \
        acc00 = fmaf(fmaxf(a0.x+b0.x,0.f),w.x,acc00); acc00 = fmaf(fmaxf(a0.y+b0.y,0.f),w.y,acc00); \
        acc00 = fmaf(fmaxf(a0.z+b0.z,0.f),w.z,acc00); acc00 = fmaf(fmaxf(a0.w+b0.w,0.f),w.w,acc00); \
        acc01 = fmaf(fmaxf(a0.x+b1.x,0.f),w.x,acc01); acc01 = fmaf(fmaxf(a0.y+b1.y,0.f),w.y,acc01); \
        acc01 = fmaf(fmaxf(a0.z+b1.z,0.f),w.z,acc01); acc01 = fmaf(fmaxf(a0.w+b1.w,0.f),w.w,acc01); \
        acc10 = fmaf(fmaxf(a1.x+b0.x,0.f),w.x,acc10); acc10 = fmaf(fmaxf(a1.y+b0.y,0.f),w.y,acc10); \
        acc10 = fmaf(fmaxf(a1.z+b0.z,0.f),w.z,acc10); acc10 = fmaf(fmaxf(a1.w+b0.w,0.f),w.w,acc10); \
        acc11 = fmaf(fmaxf(a1.x+b1.x,0.f),w.x,acc11); acc11 = fmaf(fmaxf(a1.y+b1.y,0.f),w.y,acc11); \
        acc11 = fmaf(fmaxf(a1.z+b1.z,0.f),w.z,acc11); acc11 = fmaf(fmaxf(a1.w+b1.w,0.f),w.w,acc11); \
    }

// ================= 2: self pairwise (single term) =================
__global__ __launch_bounds__(256) void pairwise_self_kernel(P p)
{
    __shared__ __align__(16) float As[32 * LDW];
    __shared__ __align__(16) float Bs[32 * LDW];
    __shared__ __align__(16) float W2s[H];
    const int b = blockIdx.z, q0 = blockIdx.y * 32, k0 = blockIdx.x * 32;
    const int tid = threadIdx.x, bS = b * S;
    for (int i = tid; i < 32 * (H / 4); i += 256) {
        const int r = i >> 5, c4 = i & 31;
        ((float4*)(As + r * LDW))[c4] = ((const float4*)(p.qa + (size_t)(bS + q0 + r) * H))[c4];
        ((float4*)(Bs + r * LDW))[c4] = ((const float4*)(p.kb + (size_t)(bS + k0 + r) * H))[c4];
    }
    if (tid < H / 4) ((float4*)W2s)[tid] = ((const float4*)p.W2)[tid];
    __syncthreads();
    const int tx = tid & 15, ty = tid >> 4;
    const float* A0 = As + (2 * ty) * LDW; const float* A1 = A0 + LDW;
    const float* B0 = Bs + (2 * tx) * LDW; const float* B1 = B0 + LDW;
    float acc00 = 0.f, acc01 = 0.f, acc10 = 0.f, acc11 = 0.f;
    #pragma unroll 4
    for (int h = 0; h < H; h += 4) PW_STEP(A0, A1, B0, B1);
    const size_t base = (size_t)(bS + q0 + 2 * ty) * S + (k0 + 2 * tx);
    *(float2*)(p.sbuf + base)     = make_float2(acc00, acc01);
    *(float2*)(p.sbuf + base + S) = make_float2(acc10, acc11);
}

// ================= 4: cross pairwise, both symmetric terms =================
__global__ __launch_bounds__(256) void pairwise_cross2_kernel(P p)
{
    __shared__ __align__(16) float As[32 * LDW];
    __shared__ __align__(16) float Bs[32 * LDW];
    __shared__ __align__(16) float W2s[H];
    const int b = blockIdx.z, q0 = blockIdx.y * 32, k0 = blockIdx.x * 32;
    const int tid = threadIdx.x, bS = b * S;
    const int tx = tid & 15, ty = tid >> 4;
    const float* A0 = As + (2 * ty) * LDW; const float* A1 = A0 + LDW;
    const float* B0 = Bs + (2 * tx) * LDW; const float* B1 = B0 + LDW;
    float acc00 = 0.f, acc01 = 0.f, acc10 = 0.f, acc11 = 0.f;

    for (int i = tid; i < 32 * (H / 4); i += 256) {
        const int r = i >> 5, c4 = i & 31;
        ((float4*)(As + r * LDW))[c4] = ((const float4*)(p.qa2 + (size_t)(bS + q0 + r) * H))[c4];
        ((float4*)(Bs + r * LDW))[c4] = ((const float4*)(p.kb2 + (size_t)(bS + k0 + r) * H))[c4];
    }
    if (tid < H / 4) ((float4*)W2s)[tid] = ((const float4*)p.W2)[tid];
    __syncthreads();
    #pragma unroll 4
    for (int h = 0; h < H; h += 4) PW_STEP(A0, A1, B0, B1);
    __syncthreads();
    for (int i = tid; i < 32 * (H / 4); i += 256) {
        const int r = i >> 5, c4 = i & 31;
        ((float4*)(As + r * LDW))[c4] = ((const float4*)(p.qb2 + (size_t)(bS + q0 + r) * H))[c4];
        ((float4*)(Bs + r * LDW))[c4] = ((const float4*)(p.ka2 + (size_t)(bS + k0 + r) * H))[c4];
    }
    __syncthreads();
    #pragma unroll 4
    for (int h = 0; h < H; h += 4) PW_STEP(A0, A1, B0, B1);
    const size_t base = (size_t)(bS + q0 + 2 * ty) * S + (k0 + 2 * tx);
    *(float2*)(p.sbuf2 + base)     = make_float2(acc00, acc01);
    *(float2*)(p.sbuf2 + base + S) = make_float2(acc10, acc11);
}

// ================= 3/5: softmax(+sym)+AV+outproj+res+LN (+q-side chain) =================
template<bool SYM, bool QPROJ>
__global__ __launch_bounds__(256) void attn_tail_kernel(P p)
{
    __shared__ float s8[8 * 256];
    __shared__ float aoS[8 * 128];   // AV result; later reused as q2w
    __shared__ float o1S[8 * 128];
    const float* Sin  = SYM ? p.sbuf : p.sbuf2;
    const float* mask = SYM ? p.com_mask : p.dec_mask;
    const float* V    = SYM ? p.xw : p.kv2w;
    const float* Wd   = SYM ? p.Wd1 : p.Wd2;
    const float* bd   = SYM ? p.bd1 : p.bd2;
    const float* res  = SYM ? p.x : p.out1;
    const float* lg   = SYM ? p.ln1g : p.ln2g;
    const float* lb   = SYM ? p.ln1b : p.ln2b;
    float* outp       = SYM ? p.out1 : p.out2;

    const int tid = threadIdx.x;
    const int r0 = blockIdx.x * 8, b = r0 >> 8, bS = b * S;

    for (int i = tid; i < 8 * 256; i += 256) {
        const int r = i >> 8, k = i & 255;
        const int row = r0 + r, q = row & 255;
        float l = Sin[(size_t)row * S + k];
        if (SYM) l += Sin[(size_t)(bS + k) * S + q];
        l += mask[(size_t)row * S + k] * NEGV;
        s8[i] = l;
    }
    __syncthreads();
    {
        const int g = tid >> 5, c = tid & 31;
        float* rowp = s8 + g * 256;
        float m = -INFINITY;
        for (int k = c; k < 256; k += 32) m = fmaxf(m, rowp[k]);
        for (int o = 16; o; o >>= 1) m = fmaxf(m, __shfl_xor(m, o, 32));
        float s = 0.f;
        for (int k = c; k < 256; k += 32) { const float e = __expf(rowp[k] - m); rowp[k] = e; s += e; }
        for (int o = 16; o; o >>= 1) s += __shfl_xor(s, o, 32);
        const float rinv = 1.f / s;
        for (int k = c; k < 256; k += 32) rowp[k] *= rinv;
    }
    __syncthreads();
    const int lr = tid >> 5, c4 = tid & 31;
    {
        const float4* V4 = (const float4*)(V + (size_t)bS * D);
        float4 acc = make_float4(0.f, 0.f, 0.f, 0.f);
        #pragma unroll 8
        for (int k = 0; k < 256; ++k) {
            const float a = s8[lr * 256 + k];
            const float4 v = V4[k * 32 + c4];
            acc.x = fmaf(a, v.x, acc.x); acc.y = fmaf(a, v.y, acc.y);
            acc.z = fmaf(a, v.z, acc.z); acc.w = fmaf(a, v.w, acc.w);
        }
        ((float4*)(aoS + lr * 128))[c4] = acc;
    }
    __syncthreads();
    {
        float4 o = mm8(aoS, Wd, bd, lr, c4);
        const float4 r4 = ((const float4*)(res + (size_t)(r0 + lr) * 128))[c4];
        const float x0 = o.x + r4.x, x1 = o.y + r4.y, x2 = o.z + r4.z, x3 = o.w + r4.w;
        float s  = x0 + x1 + x2 + x3;
        float s2 = x0 * x0 + x1 * x1 + x2 * x2 + x3 * x3;
        for (int of = 16; of; of >>= 1) { s += __shfl_xor(s, of, 32); s2 += __shfl_xor(s2, of, 32); }
        const float m = s * (1.f / 128), var = s2 * (1.f / 128) - m * m;
        const float rs = rsqrtf(var + LN_EPS);
        const float4 gv = ((const float4*)lg)[c4], bv = ((const float4*)lb)[c4];
        float4 o4;
        o4.x = (x0 - m) * rs * gv.x + bv.x; o4.y = (x1 - m) * rs * gv.y + bv.y;
        o4.z = (x2 - m) * rs * gv.z + bv.z; o4.w = (x3 - m) * rs * gv.w + bv.w;
        ((float4*)outp)[(size_t)(r0 + lr) * 32 + c4] = o4;
        if (QPROJ) { ((float4*)(o1S + lr * 128))[c4] = o4; }
    }
    if (QPROJ) {
        // q2w = out1@Ww2+bw2 (LDS), then qa2 = q2w@W1q+b1, qb2 = q2w@W1k+b1
        __syncthreads();
        const float4 w = mm8(o1S, p.Ww2, p.bw2, lr, c4);
        ((float4*)(aoS + lr * 128))[c4] = w;   // reuse aoS as q2w
        __syncthreads();
        const float4 q = mm8(aoS, p.W1q, p.b1, lr, c4);
        ((float4*)p.qa2)[(size_t)(r0 + lr) * 32 + c4] = q;
        const float4 k = mm8(aoS, p.W1k, p.b1, lr, c4);
        ((float4*)p.qb2)[(size_t)(r0 + lr) * 32 + c4] = k;
    }
}

// ================= 6: ffn, register-tiled (weights loaded once/block) =================
__global__ __launch_bounds__(256) void ffn_kernel(P p)
{
    __shared__ float o2S[4 * 128];        // 2 KB
    __shared__ float hidP[2 * 4 * 512];   // 16 KB partials; [0..2048) becomes hidden
    __shared__ float part[8 * 4 * 128];   // 16 KB ffn2 partials
    const int r0 = blockIdx.x * 4, tid = threadIdx.x;

    if (tid < 128) ((float4*)o2S)[tid] = ((const float4*)(p.out2 + (size_t)r0 * 128))[tid];
    __syncthreads();

    // ffn1: thread owns float4-col c4 of 512 (128 cols), k-half kh; 4-row regs
    {
        const int c4 = tid & 127, kh = tid >> 7;
        const float4* Wf1_4 = (const float4*)p.Wf1;
        float4 a0 = make_float4(0.f,0.f,0.f,0.f), a1 = a0, a2 = a0, a3 = a0;
        const int kbase = kh * 64;
        #pragma unroll 8
        for (int k = 0; k < 64; ++k) {
            const int kk = kbase + k;
            const float4 w = Wf1_4[kk * 128 + c4];
            const float s0 = o2S[kk], s1 = o2S[128 + kk], s2 = o2S[256 + kk], s3 = o2S[384 + kk];
            a0.x = fmaf(s0, w.x, a0.x); a0.y = fmaf(s0, w.y, a0.y); a0.z = fmaf(s0, w.z, a0.z); a0.w = fmaf(s0, w.w, a0.w);
            a1.x = fmaf(s1, w.x, a1.x); a1.y = fmaf(s1, w.y, a1.y); a1.z = fmaf(s1, w.z, a1.z); a1.w = fmaf(s1, w.w, a1.w);
            a2.x = fmaf(s2, w.x, a2.x); a2.y = fmaf(s2, w.y, a2.y); a2.z = fmaf(s2, w.z, a2.z); a2.w = fmaf(s2, w.w, a2.w);
            a3.x = fmaf(s3, w.x, a3.x); a3.y = fmaf(s3, w.y, a3.y); a3.z = fmaf(s3, w.z, a3.z); a3.w = fmaf(s3, w.w, a3.w);
        }
        float4* h4 = (float4*)(hidP + kh * 2048);
        h4[0 * 128 + c4] = a0; h4[1 * 128 + c4] = a1;
        h4[2 * 128 + c4] = a2; h4[3 * 128 + c4] = a3;
    }
    __syncthreads();
    // combine k-halves + bias + relu -> hidden in hidP[0..2048)
    for (int i = tid; i < 2048; i += 256) {
        const int c = i & 511;
        hidP[i] = fmaxf(hidP[i] + hidP[2048 + i] + p.bf1[c], 0.f);
    }
    __syncthreads();

    // ffn2: thread owns float4-col c4 of 128 (32 cols), k-group kg (8x64); 4-row regs
    {
        const int c4 = tid & 31, kg = tid >> 5;
        const float4* Wf2_4 = (const float4*)p.Wf2;
        float4 a0 = make_float4(0.f,0.f,0.f,0.f), a1 = a0, a2 = a0, a3 = a0;
        const int kbase = kg * 64;
        #pragma unroll 8
        for (int k = 0; k < 64; ++k) {
            const int kk = kbase + k;
            const float4 w = Wf2_4[kk * 32 + c4];
            const float s0 = hidP[kk], s1 = hidP[512 + kk], s2 = hidP[1024 + kk], s3 = hidP[1536 + kk];
            a0.x = fmaf(s0, w.x, a0.x); a0.y = fmaf(s0, w.y, a0.y); a0.z = fmaf(s0, w.z, a0.z); a0.w = fmaf(s0, w.w, a0.w);
            a1.x = fmaf(s1, w.x, a1.x); a1.y = fmaf(s1, w.y, a1.y); a1.z = fmaf(s1, w.z, a1.z); a1.w = fmaf(s1, w.w, a1.w);
            a2.x = fmaf(s2, w.x, a2.x); a2.y = fmaf(s2, w.y, a2.y); a2.z = fmaf(s2, w.z, a2.z); a2.w = fmaf(s2, w.w, a2.w);
            a3.x = fmaf(s3, w.x, a3.x); a3.y = fmaf(s3, w.y, a3.y); a3.z = fmaf(s3, w.z, a3.z); a3.w = fmaf(s3, w.w, a3.w);
        }
        float4* p4 = (float4*)part;
        p4[(kg * 4 + 0) * 32 + c4] = a0; p4[(kg * 4 + 1) * 32 + c4] = a1;
        p4[(kg * 4 + 2) * 32 + c4] = a2; p4[(kg * 4 + 3) * 32 + c4] = a3;
    }
    __syncthreads();

    if (tid < 128) {
        const int row = tid >> 5, c4 = tid & 31;
        const float4* p4 = (const float4*)part;
        float4 sum = ((const float4*)p.bf2)[c4];
        #pragma unroll
        for (int kg = 0; kg < 8; ++kg) {
            const float4 v = p4[(kg * 4 + row) * 32 + c4];
            sum.x += v.x; sum.y += v.y; sum.z += v.z; sum.w += v.w;
        }
        const float4 r4 = ((const float4*)o2S)[row * 32 + c4];
        const float x0 = sum.x + r4.x, x1 = sum.y + r4.y, x2 = sum.z + r4.z, x3 = sum.w + r4.w;
        float s  = x0 + x1 + x2 + x3;
        float s2 = x0 * x0 + x1 * x1 + x2 * x2 + x3 * x3;
        for (int of = 16; of; of >>= 1) { s += __shfl_xor(s, of, 32); s2 += __shfl_xor(s2, of, 32); }
        const float m = s * (1.f / 128), var = s2 * (1.f / 128) - m * m;
        const float rs = rsqrtf(var + LN_EPS);
        const float4 gv = ((const float4*)p.ln3g)[c4], bv = ((const float4*)p.ln3b)[c4];
        float4 o4;
        o4.x = (x0 - m) * rs * gv.x + bv.x; o4.y = (x1 - m) * rs * gv.y + bv.y;
        o4.z = (x2 - m) * rs * gv.z + bv.z; o4.w = (x3 - m) * rs * gv.w + bv.w;
        ((float4*)p.out)[(size_t)(r0 + row) * 32 + c4] = o4;
    }
}

extern "C" void kernel_launch(void* const* d_in, const int* in_sizes, int n_in,
                              void* d_out, int out_size, void* d_ws, size_t ws_size,
                              hipStream_t stream) {
    (void)in_sizes; (void)n_in; (void)out_size; (void)ws_size;
    P p;
    p.x        = (const float*)d_in[0];
    p.enc      = (const float*)d_in[1];
    p.com_mask = (const float*)d_in[2];
    p.dec_mask = (const float*)d_in[3];
    p.W1q = (const float*)d_in[4];
    p.W1k = (const float*)d_in[5];
    p.b1  = (const float*)d_in[6];
    p.W2  = (const float*)d_in[7];
    // d_in[8] = b2: per-row constant -> dropped (softmax shift invariance)
    p.Ww1 = (const float*)d_in[9];
    p.bw1 = (const float*)d_in[10];
    p.Wd1 = (const float*)d_in[11];
    p.bd1 = (const float*)d_in[12];
    p.Ww2 = (const float*)d_in[13];
    p.bw2 = (const float*)d_in[14];
    p.Wd2 = (const float*)d_in[15];
    p.bd2 = (const float*)d_in[16];
    p.Wf1 = (const float*)d_in[17];
    p.bf1 = (const float*)d_in[18];
    p.Wf2 = (const float*)d_in[19];
    p.bf2 = (const float*)d_in[20];
    p.ln1g = (const float*)d_in[21];
    p.ln1b = (const float*)d_in[22];
    p.ln2g = (const float*)d_in[23];
    p.ln2b = (const float*)d_in[24];
    p.ln3g = (const float*)d_in[25];
    p.ln3b = (const float*)d_in[26];
    p.out  = (float*)d_out;

    float* ws = (float*)d_ws;
    const size_t RD  = (size_t)R * D;      // 131072
    const size_t SSz = (size_t)B * S * S;  // 262144
    p.xw    = ws;
    p.qa    = p.xw    + RD;
    p.kb    = p.qa    + RD;
    p.kv2w  = p.kb    + RD;
    p.kb2   = p.kv2w  + RD;
    p.ka2   = p.kb2   + RD;
    p.qa2   = p.ka2   + RD;
    p.qb2   = p.qa2   + RD;
    p.sbuf  = p.qb2   + RD;    // SSz
    p.sbuf2 = p.sbuf  + SSz;   // SSz
    p.out1  = p.sbuf2 + SSz;
    p.out2  = p.out1  + RD;

    proj3_kernel<<<dim3(R / 8, 2), 256, 0, stream>>>(p);
    pairwise_self_kernel<<<dim3(8, 8, 4), 256, 0, stream>>>(p);
    attn_tail_kernel<true, true><<<R / 8, 256, 0, stream>>>(p);
    pairwise_cross2_kernel<<<dim3(8, 8, 4), 256, 0, stream>>>(p);
    attn_tail_kernel<false, false><<<R / 8, 256, 0, stream>>>(p);
    ffn_kernel<<<R / 4, 256, 0, stream>>>(p);
}